// Round 1
// 1410.170 us; speedup vs baseline: 7.0901x; 7.0901x over previous
//
#include <hip/hip_runtime.h>

typedef unsigned short u16;
typedef unsigned int u32;
typedef __bf16 bf16x8 __attribute__((ext_vector_type(8)));
typedef float f32x4 __attribute__((ext_vector_type(4)));

union FragU { uint4 u; bf16x8 v; };

__device__ __forceinline__ u16 f2bf(float f) {
  union { float f; u32 u; } c; c.f = f;
  u32 u = c.u;
  return (u16)((u + 0x7fffu + ((u >> 16) & 1u)) >> 16);
}

__device__ __forceinline__ bf16x8 ldfrag(const u16* p) {
  FragU t; t.u = *(const uint4*)p; return t.v;
}

// Fine-grained device-coherent accesses: sc0 sc1 bypasses L1+L2, data is
// served/acked at the device-coherent point (L3/MALL). This replaces the
// agent-scope fences (buffer_wbl2 / buffer_inv whole-L2 maintenance) that
// dominated per-step latency.
__device__ __forceinline__ void ldA6_coh(const u16* p, FragU* a) {
  asm volatile(
      "global_load_dwordx4 %0, %6, off sc0 sc1\n\t"
      "global_load_dwordx4 %1, %6, off offset:64 sc0 sc1\n\t"
      "global_load_dwordx4 %2, %6, off offset:128 sc0 sc1\n\t"
      "global_load_dwordx4 %3, %6, off offset:192 sc0 sc1\n\t"
      "global_load_dwordx4 %4, %6, off offset:256 sc0 sc1\n\t"
      "global_load_dwordx4 %5, %6, off offset:320 sc0 sc1\n\t"
      "s_waitcnt vmcnt(0)"
      : "=&v"(a[0].u), "=&v"(a[1].u), "=&v"(a[2].u),
        "=&v"(a[3].u), "=&v"(a[4].u), "=&v"(a[5].u)
      : "v"(p)
      : "memory");
}

__device__ __forceinline__ void st_bf16_coh(u16* p, u16 v) {
  u32 vv = v;
  asm volatile("global_store_short %0, %1, off sc0 sc1" :: "v"(p), "v"(vv) : "memory");
}

__device__ __forceinline__ void st_flag_coh(int* p, int v) {
  asm volatile("global_store_dword %0, %1, off sc0 sc1" :: "v"(p), "v"(v) : "memory");
}

__device__ __forceinline__ int ld_flag_coh(const int* p) {
  int v;
  asm volatile("global_load_dword %0, %1, off sc0 sc1\n\ts_waitcnt vmcnt(0)"
               : "=&v"(v) : "v"(p) : "memory");
  return v;
}

// ---------------------------------------------------------------------------
// Sizes
//   d_out: h1s [0, 52428800) | h2s [52428800, 78643200) | outputs [78643200, 104857600)
//   ws: wcat(bf16 1536x1536) | wh(bf16 1536x512) | woutb(bf16 512x1536) |
//       bcat(f32 1536) | win2(f32 1536x2) | h0(f32 256x1536) |
//       state(bf16 2x256x1536) | bar(1024 int: flag[mb][g] at (mb*16+g)*4)
// ---------------------------------------------------------------------------

__global__ void pack_kernel(const float* __restrict__ Wrec1, const float* __restrict__ Wrec2,
                            const float* __restrict__ W12,   const float* __restrict__ W21,
                            const float* __restrict__ Wh1,   const float* __restrict__ Wh2,
                            const float* __restrict__ Wout,
                            const float* __restrict__ bin1,  const float* __restrict__ bin2,
                            const float* __restrict__ brec1, const float* __restrict__ brec2,
                            const float* __restrict__ b12,   const float* __restrict__ b21,
                            const float* __restrict__ Win1,  const float* __restrict__ Win2,
                            u16* __restrict__ wcat, u16* __restrict__ wh, u16* __restrict__ woutb,
                            float* __restrict__ bcat, float* __restrict__ win2, int* __restrict__ bar)
{
  int i = blockIdx.x * 256 + threadIdx.x;
  if (i < 2359296) {               // W_cat[n][k]: row n = output neuron, k over [h1|h2]
    int n = i / 1536, k = i - n * 1536;
    float v;
    if (n < 1024) v = (k < 1024) ? Wrec1[n * 1024 + k] : W21[n * 512 + (k - 1024)];
    else { int n2 = n - 1024; v = (k < 1024) ? W12[n2 * 1024 + k] : Wrec2[n2 * 512 + (k - 1024)]; }
    wcat[i] = f2bf(v);
    return;
  }
  i -= 2359296;
  if (i < 786432) {                // Wh[n][o]
    int n = i >> 9, k = i & 511;
    wh[i] = f2bf(n < 1024 ? Wh1[n * 512 + k] : Wh2[(n - 1024) * 512 + k]);
    return;
  }
  i -= 786432;
  if (i < 786432) { woutb[i] = f2bf(Wout[i]); return; }
  i -= 786432;
  if (i < 1536) {                  // combined bias: b_in + b_rec + b_cross
    bcat[i] = (i < 1024) ? (bin1[i] + brec1[i] + b21[i])
                         : (bin2[i - 1024] + brec2[i - 1024] + b12[i - 1024]);
    return;
  }
  i -= 1536;
  if (i < 3072) {                  // input-projection coeffs
    int n = i >> 1, c = i & 1;
    win2[i] = (n < 1024) ? Win1[n * 2 + c] : Win2[(n - 1024) * 2 + c];
    return;
  }
  i -= 3072;
  if (i < 1024) bar[i] = 0;        // step flags (ws is poisoned each launch)
}

// ---------------------------------------------------------------------------
// h0 = pc0 @ [Wh1|Wh2]^T   (M=256, N=1536, K=512); writes fp32 h0 + bf16 state[0]
// grid 96 = 4 mt x 24 nt, block 256 (4 waves, each 32x32 quadrant of 64x64 tile)
// ---------------------------------------------------------------------------
__global__ __launch_bounds__(256) void h0_kernel(const float* __restrict__ pc0,
                                                 const u16* __restrict__ wh,
                                                 float* __restrict__ h0, u16* __restrict__ st0)
{
  __shared__ u16 As[64 * 32];
  __shared__ u16 Bs[64 * 32];
  int tid = threadIdx.x;
  int lane = tid & 63, w = tid >> 6;
  int q = lane >> 4, col = lane & 15;
  int mt = blockIdx.x & 3, nt = blockIdx.x >> 2;
  int wm = w & 1, wn = w >> 1;
  f32x4 zero = {0.f, 0.f, 0.f, 0.f};
  f32x4 acc[2][2];
#pragma unroll
  for (int a = 0; a < 2; ++a)
#pragma unroll
    for (int b = 0; b < 2; ++b) acc[a][b] = zero;

  for (int k0 = 0; k0 < 512; k0 += 32) {
    __syncthreads();
#pragma unroll
    for (int it = 0; it < 2; ++it) {         // A: 64x32 fp32 -> bf16 LDS
      int f = tid + 256 * it; int r = f >> 3, c4 = f & 7;
      float4 v = *(const float4*)(pc0 + (mt * 64 + r) * 512 + k0 + c4 * 4);
      u16* d = &As[r * 32 + c4 * 4];
      d[0] = f2bf(v.x); d[1] = f2bf(v.y); d[2] = f2bf(v.z); d[3] = f2bf(v.w);
    }
    {                                        // B: 64x32 bf16
      int r = tid >> 2, c8 = tid & 3;
      *(uint4*)&Bs[r * 32 + c8 * 8] = *(const uint4*)(wh + (nt * 64 + r) * 512 + k0 + c8 * 8);
    }
    __syncthreads();
    bf16x8 af[2], bfr[2];
#pragma unroll
    for (int mi = 0; mi < 2; ++mi) af[mi] = ldfrag(&As[(wm * 32 + mi * 16 + col) * 32 + q * 8]);
#pragma unroll
    for (int ni = 0; ni < 2; ++ni) bfr[ni] = ldfrag(&Bs[(wn * 32 + ni * 16 + col) * 32 + q * 8]);
#pragma unroll
    for (int mi = 0; mi < 2; ++mi)
#pragma unroll
      for (int ni = 0; ni < 2; ++ni)
        acc[mi][ni] = __builtin_amdgcn_mfma_f32_16x16x32_bf16(af[mi], bfr[ni], acc[mi][ni], 0, 0, 0);
  }
#pragma unroll
  for (int mi = 0; mi < 2; ++mi)
#pragma unroll
    for (int ni = 0; ni < 2; ++ni)
#pragma unroll
      for (int v = 0; v < 4; ++v) {
        int m = mt * 64 + wm * 32 + mi * 16 + q * 4 + v;
        int n = nt * 64 + wn * 32 + ni * 16 + col;
        float val = acc[mi][ni][v];
        h0[m * 1536 + n] = val;
        st0[m * 1536 + n] = f2bf(val);
      }
}

// ---------------------------------------------------------------------------
// Persistent recurrent kernel.
// 256 blocks x 512 thr. Block = (mb = batch group of 16 rows, nb = 96 neurons).
// W register-stationary: wave w holds 96n x 192k slice as 36 B-fragments.
// Per step: 6 A-frags (device-coherent sc0sc1 loads from L3) -> 36 MFMA ->
// LDS K-reduction -> tanh/leaky update -> sc0sc1 state write -> vmcnt drain ->
// monotonic per-block flag publish -> 16 lanes poll group flags.
// No agent fences / no L2 writeback-invalidate anywhere in the loop.
// ---------------------------------------------------------------------------
__global__ __launch_bounds__(512, 2) void rnn_kernel(
    const u16* __restrict__ wcat, const float* __restrict__ bcat, const float* __restrict__ win2,
    const float* __restrict__ x, const float* __restrict__ h0,
    u16* __restrict__ state, int* __restrict__ bar, float* __restrict__ out)
{
  __shared__ float P[12800];                 // 8 waves x 16 rows x (96+pad4) partials
  int tid = threadIdx.x;
  int lane = tid & 63, w = tid >> 6;
  int q = lane >> 4, col = lane & 15;
  int mb = blockIdx.x & 15, nb = blockIdx.x >> 4;   // mb%8 ~ XCD: group stays on one XCD

  bf16x8 wf[6][6];                           // persistent weight fragments (144 VGPR)
  {
    const u16* wp = wcat + (nb * 96 + col) * 1536 + w * 192 + q * 8;
#pragma unroll
    for (int ni = 0; ni < 6; ++ni)
#pragma unroll
      for (int kc = 0; kc < 6; ++kc)
        wf[ni][kc] = ldfrag(wp + ni * (16 * 1536) + kc * 32);
  }

  // per-lane epilogue constants: 3 state elements per lane (16x96 over 512 threads)
  int poff[3], hoff[3], ooff[3], rs[3];
  float bias_[3], wi0_[3], wi1_[3], cm_[3], ca_[3], hreg[3];
  const float* xp_[3];
#pragma unroll
  for (int e = 0; e < 3; ++e) {
    int idx = e * 64 + lane;
    int r = w * 2 + idx / 96;                // block-local row 0..15
    int c = idx - (idx / 96) * 96;           // 0..95
    int ng = nb * 96 + c;                    // global neuron
    int b = mb * 16 + r;                     // global batch row
    poff[e] = r * 100 + c;
    hoff[e] = b * 1536 + ng;
    bias_[e] = bcat[ng];
    wi0_[e] = win2[2 * ng]; wi1_[e] = win2[2 * ng + 1];
    float al = (ng < 1024) ? 0.1f : 0.05f;
    ca_[e] = al; cm_[e] = 1.f - al;
    ooff[e] = (ng < 1024) ? (b * 204800 + ng) : (52428800 + b * 102400 + (ng - 1024));
    rs[e] = (ng < 1024) ? 1024 : 512;
    xp_[e] = x + b * 400;
    hreg[e] = h0[hoff[e]];
  }

  int aoff = (mb * 16 + col) * 1536 + w * 192 + q * 8;
  int* myflag = bar + (mb * 16 + nb) * 4;    // monotonic step flag, 16B stride

  for (int t = 0; t < 200; ++t) {
    const u16* hr = state + ((t & 1) ? 393216 : 0) + aoff;
    FragU a6[6];
    ldA6_coh(hr, a6);                        // device-coherent A-frag loads (L3)

    if (t > 0) {                             // deferred fp32 history write for t-1
                                             // (issued after the load drain; acked
                                             // by the pre-flag drain below)
#pragma unroll
      for (int e = 0; e < 3; ++e) out[ooff[e] + (t - 1) * rs[e]] = hreg[e];
    }

    bf16x8 af[6];
#pragma unroll
    for (int kc = 0; kc < 6; ++kc) af[kc] = a6[kc].v;
    f32x4 zero = {0.f, 0.f, 0.f, 0.f};
    f32x4 acc[6];
#pragma unroll
    for (int ni = 0; ni < 6; ++ni) acc[ni] = zero;
#pragma unroll
    for (int kc = 0; kc < 6; ++kc)
#pragma unroll
      for (int ni = 0; ni < 6; ++ni)
        acc[ni] = __builtin_amdgcn_mfma_f32_16x16x32_bf16(af[kc], wf[ni][kc], acc[ni], 0, 0, 0);
#pragma unroll
    for (int ni = 0; ni < 6; ++ni)
#pragma unroll
      for (int v = 0; v < 4; ++v)
        P[(w * 16 + q * 4 + v) * 100 + ni * 16 + col] = acc[ni][v];
    __syncthreads();

    u16* hw = state + ((t & 1) ? 0 : 393216);
#pragma unroll
    for (int e = 0; e < 3; ++e) {
      float s = 0.f;
#pragma unroll
      for (int p = 0; p < 8; ++p) s += P[p * 1600 + poff[e]];
      float2 xv = *(const float2*)(xp_[e] + 2 * t);
      float tt = s + bias_[e] + xv.x * wi0_[e] + xv.y * wi1_[e];
      float th = tanhf(tt);
      hreg[e] = cm_[e] * hreg[e] + ca_[e] * th;
      st_bf16_coh(&hw[hoff[e]], f2bf(hreg[e]));   // device-coherent state write
    }

    if (t < 199) {
      // release: all this thread's coherent stores acked at the coherence point
      asm volatile("s_waitcnt vmcnt(0)" ::: "memory");
      __syncthreads();                       // whole block's state visible
      if (tid == 0) st_flag_coh(myflag, t + 1);   // publish (monotonic, no reset)
      if (tid < 16) {                        // wait for all 16 blocks of the group
        const int* fp = bar + (mb * 16 + tid) * 4;
        while (ld_flag_coh(fp) < t + 1) { }
      }
      __syncthreads();
    }
  }
#pragma unroll
  for (int e = 0; e < 3; ++e) out[ooff[e] + 199 * rs[e]] = hreg[e];
}

// ---------------------------------------------------------------------------
// outputs = [h1s|h2s] @ W_out^T   (M=51200, N=512, K=1536)
// 800 blocks, tile 64(m) x 512(n, full): W_out stays L2-resident, A streamed once.
// ---------------------------------------------------------------------------
__global__ __launch_bounds__(256, 2) void out_kernel(const float* __restrict__ h1s,
                                                     const float* __restrict__ h2s,
                                                     const u16* __restrict__ woutb,
                                                     float* __restrict__ outp)
{
  __shared__ u16 As[64 * 32];
  __shared__ u16 Bs[512 * 32];
  int tid = threadIdx.x;
  int lane = tid & 63, w = tid >> 6;
  int q = lane >> 4, col = lane & 15;
  int mt = blockIdx.x;
  f32x4 zero = {0.f, 0.f, 0.f, 0.f};
  f32x4 acc[4][8];
#pragma unroll
  for (int a = 0; a < 4; ++a)
#pragma unroll
    for (int b = 0; b < 8; ++b) acc[a][b] = zero;

  for (int k0 = 0; k0 < 1536; k0 += 32) {
    __syncthreads();
    const float* Asrc; int lda;
    if (k0 < 1024) { Asrc = h1s + k0; lda = 1024; }
    else           { Asrc = h2s + (k0 - 1024); lda = 512; }
#pragma unroll
    for (int it = 0; it < 2; ++it) {         // A: 64x32 fp32 -> bf16
      int f = tid + 256 * it; int r = f >> 3, c4 = f & 7;
      float4 v = *(const float4*)(Asrc + (mt * 64 + r) * lda + c4 * 4);
      u16* d = &As[r * 32 + c4 * 4];
      d[0] = f2bf(v.x); d[1] = f2bf(v.y); d[2] = f2bf(v.z); d[3] = f2bf(v.w);
    }
#pragma unroll
    for (int it = 0; it < 8; ++it) {         // B: 512x32 bf16
      int f = tid + 256 * it; int r = f >> 2, c8 = f & 3;
      *(uint4*)&Bs[r * 32 + c8 * 8] = *(const uint4*)(woutb + r * 1536 + k0 + c8 * 8);
    }
    __syncthreads();
    bf16x8 af[4], bfr[8];
#pragma unroll
    for (int mi = 0; mi < 4; ++mi) af[mi] = ldfrag(&As[(mi * 16 + col) * 32 + q * 8]);
#pragma unroll
    for (int ni = 0; ni < 8; ++ni) bfr[ni] = ldfrag(&Bs[(w * 128 + ni * 16 + col) * 32 + q * 8]);
#pragma unroll
    for (int mi = 0; mi < 4; ++mi)
#pragma unroll
      for (int ni = 0; ni < 8; ++ni)
        acc[mi][ni] = __builtin_amdgcn_mfma_f32_16x16x32_bf16(af[mi], bfr[ni], acc[mi][ni], 0, 0, 0);
  }
#pragma unroll
  for (int mi = 0; mi < 4; ++mi)
#pragma unroll
    for (int ni = 0; ni < 8; ++ni)
#pragma unroll
      for (int v = 0; v < 4; ++v)
        outp[(mt * 64 + mi * 16 + q * 4 + v) * 512 + w * 128 + ni * 16 + col] = acc[mi][ni][v];
}

extern "C" void kernel_launch(void* const* d_in, const int* in_sizes, int n_in,
                              void* d_out, int out_size, void* d_ws, size_t ws_size,
                              hipStream_t stream) {
  const float* inputs = (const float*)d_in[0];
  const float* pc0   = (const float*)d_in[1];
  const float* Win1  = (const float*)d_in[2];
  const float* bin1  = (const float*)d_in[3];
  const float* Win2  = (const float*)d_in[4];
  const float* bin2  = (const float*)d_in[5];
  const float* Wrec1 = (const float*)d_in[6];
  const float* brec1 = (const float*)d_in[7];
  const float* Wrec2 = (const float*)d_in[8];
  const float* brec2 = (const float*)d_in[9];
  const float* W12   = (const float*)d_in[10];
  const float* b12   = (const float*)d_in[11];
  const float* W21   = (const float*)d_in[12];
  const float* b21   = (const float*)d_in[13];
  const float* Wout  = (const float*)d_in[14];
  const float* Wh1   = (const float*)d_in[15];
  const float* Wh2   = (const float*)d_in[16];

  char* ws = (char*)d_ws;
  u16*   wcat  = (u16*)(ws + 0);
  u16*   wh    = (u16*)(ws + 4718592);
  u16*   woutb = (u16*)(ws + 6291456);
  float* bcat  = (float*)(ws + 7864320);
  float* win2  = (float*)(ws + 7870464);
  float* h0    = (float*)(ws + 7882752);
  u16*   state = (u16*)(ws + 9455616);
  int*   bar   = (int*)(ws + 11028480);

  float* out = (float*)d_out;

  pack_kernel<<<15382, 256, 0, stream>>>(Wrec1, Wrec2, W12, W21, Wh1, Wh2, Wout,
                                         bin1, bin2, brec1, brec2, b12, b21, Win1, Win2,
                                         wcat, wh, woutb, bcat, win2, bar);
  h0_kernel<<<96, 256, 0, stream>>>(pc0, wh, h0, state);
  rnn_kernel<<<256, 512, 0, stream>>>(wcat, bcat, win2, inputs, h0, state, bar, out);
  out_kernel<<<800, 256, 0, stream>>>(out, out + 52428800, woutb, out + 78643200);
}